// Round 14
// baseline (57.390 us; speedup 1.0000x reference)
//
#include <hip/hip_runtime.h>
#include <hip/hip_bf16.h>
#include <cstdint>

// HopfieldLayer: out = attn(attn(R,Y,Y), Y, Y), H=8, E=64, scale 1/8.
// R14: strict bisect of R13's NaN. Base = R12 VERBATIM (proven 55.7 us) with
// ONLY the lacc ones-MFMA removed -> VALU ls accumulation + 2 epilogue shfls
// (-8 AGPR, -4 VGPR ones-frag => ~118 regs, targets the 128-reg tier for
// 4 waves/SIMD). R13's DMA offset:64 consolidation and tr-read hoisting are
// REVERTED (both NaN-capable; retest in isolation later if needed).

typedef __attribute__((ext_vector_type(8))) short bf16x8;
typedef __attribute__((ext_vector_type(4))) short short4v;
typedef __attribute__((ext_vector_type(4))) float f32x4;

constexpr int B_ = 2, L_ = 2048, S_ = 2048, H_ = 8, E_ = 64, DM_ = 512;
constexpr int NTQ_ = 16; // 32-s tiles per S-quarter (512 s)
constexpr float SCALE2 = 0.18033688011112042f; // (1/sqrt(64)) * log2(e)
constexpr float FIXMAX = 24.0f;                // fixed softmax max (exp2 domain)

__device__ __forceinline__ ushort f2bf(float a) {
  uint32_t u = __builtin_bit_cast(uint32_t, a);
  return (ushort)((u + 0x7fffu + ((u >> 16) & 1u)) >> 16); // RNE, finite inputs
}
__device__ __forceinline__ uint32_t pkcvt(float lo, float hi) {
  uint32_t r; // D[15:0] = bf16(S0=lo), D[31:16] = bf16(S1=hi)
  asm("v_cvt_pk_bf16_f32 %0, %1, %2" : "=v"(r) : "v"(lo), "v"(hi));
  return r;
}
__device__ __forceinline__ void dma16(const ushort* g, const ushort* l) {
  __builtin_amdgcn_global_load_lds(
      (const __attribute__((address_space(1))) uint32_t*)g,
      (__attribute__((address_space(3))) uint32_t*)l, 16, 0, 0);
}

__global__ void cvt_kernel(const float* __restrict__ in, ushort* __restrict__ out, int n4) {
  int i = blockIdx.x * 256 + threadIdx.x;
  if (i >= n4) return;
  float4 v = reinterpret_cast<const float4*>(in)[i];
  ushort4 o;
  o.x = f2bf(v.x); o.y = f2bf(v.y); o.z = f2bf(v.z); o.w = f2bf(v.w);
  reinterpret_cast<ushort4*>(out)[i] = o;
}

// KV LDS tile: 32s x 64e bf16, sub-tiled for tr-reads (R8-R12-proven):
//   idx(s,e) = block*64 + (s&3)*16 + (e&15),
//   block = (((s>>2)&1)*4 + (e>>4))*4 + (s>>3)
// DMA chunk c (16 B) at byte c*16 holds s = (blk&3)*8 + ((blk>>4)&1)*4 +
//   ((c>>1)&3), e0 = ((blk>>2)&3)*16 + (c&1)*8, blk = c>>3.
__global__ __launch_bounds__(256, 4) void hopfield_kernel(
    const float* __restrict__ Rf, const ushort* __restrict__ Yb,
    float* __restrict__ outF) {
  __shared__ ushort Vq[4][2][2048]; // 32 KB; merge-partial overlay (own slices)
  __shared__ uint32_t SB[1024];     // 4 KB: ml, then q-broadcast (pass 0)

  const int tid = threadIdx.x, lane = tid & 63, wid = tid >> 6;
  const int g = lane >> 4, qi = lane & 15;
  // bijective XCD swizzle: XCD k (= orig%8) owns 128 contiguous logical wgs
  const int wg = (blockIdx.x & 7) * 128 + (blockIdx.x >> 3);
  const int qt = wg & 63, h = (wg >> 6) & 7, b = wg >> 9;

  size_t qbase[2];
#pragma unroll
  for (int set = 0; set < 2; ++set)
    qbase[set] = (size_t)(b * L_ + qt * 32 + set * 16 + qi) * DM_ + h * E_;

  // pass-0 Q frags: read R f32, scale, pack to bf16 (cvt_pk)
  bf16x8 qf[2][2];
#pragma unroll
  for (int set = 0; set < 2; ++set)
#pragma unroll
    for (int eck = 0; eck < 2; ++eck) {
      const float* s = Rf + qbase[set] + eck * 32 + 8 * g;
      float4 aa = *reinterpret_cast<const float4*>(s);
      float4 bb = *reinterpret_cast<const float4*>(s + 4);
      uint4 w;
      w.x = pkcvt(aa.x * SCALE2, aa.y * SCALE2);
      w.y = pkcvt(aa.z * SCALE2, aa.w * SCALE2);
      w.z = pkcvt(bb.x * SCALE2, bb.y * SCALE2);
      w.w = pkcvt(bb.z * SCALE2, bb.w * SCALE2);
      qf[set][eck] = __builtin_bit_cast(bf16x8, w);
    }

  const size_t ybase = (size_t)(b * S_ + wid * 512) * DM_ + h * E_;

  // per-lane DMA global sources (pre-swizzled to match the sub-tiled layout)
  const ushort* gdma[4];
#pragma unroll
  for (int i = 0; i < 4; ++i) {
    int c = i * 64 + lane, blk = c >> 3;
    int s = (blk & 3) * 8 + ((blk >> 4) & 1) * 4 + ((c >> 1) & 3);
    int e0 = ((blk >> 2) & 3) * 16 + (c & 1) * 8;
    gdma[i] = Yb + ybase + (size_t)s * DM_ + e0;
  }

  int kidx[4];
#pragma unroll
  for (int nt = 0; nt < 2; ++nt)
#pragma unroll
    for (int eck = 0; eck < 2; ++eck) {
      int s = nt * 16 + qi;
      kidx[nt * 2 + eck] = ((((s >> 2) & 1) * 4 + (eck * 2 + (g >> 1))) * 4 + (s >> 3)) * 64 +
                           (s & 3) * 16 + 8 * (g & 1);
    }

  const uint32_t vb0 = (uint32_t)(uintptr_t)(&Vq[wid][0][0]);
  float* mrg = (float*)&Vq[0][0][0];
  float* ml = (float*)&SB[0];
  ushort* qls = (ushort*)&SB[0];

  for (int pass = 0; pass < 2; ++pass) {
    f32x4 oacc[2][4];
#pragma unroll
    for (int set = 0; set < 2; ++set)
#pragma unroll
      for (int et = 0; et < 4; ++et) oacc[set][et] = f32x4{0.f, 0.f, 0.f, 0.f};
    float ls[2] = {0.f, 0.f};

    // prologue: DMA tile 0 into buffer 0 (wave-private slice)
#pragma unroll
    for (int i = 0; i < 4; ++i) dma16(gdma[i], &Vq[wid][0][i * 512]);
    int cur = 0;

    for (int t = 0; t < NTQ_; ++t) {
      asm volatile("s_waitcnt vmcnt(0)" ::: "memory"); // tile t resident
      if (t + 1 < NTQ_) { // issue next tile a full iteration ahead
        const size_t tadd = (size_t)(t + 1) * 32 * DM_;
#pragma unroll
        for (int i = 0; i < 4; ++i)
          dma16(gdma[i] + tadd, &Vq[wid][cur ^ 1][i * 512]);
      }

      const ushort* Vc = &Vq[wid][cur][0];
      const uint32_t trbase = vb0 + (uint32_t)(cur * 4096) + 8u * (uint32_t)lane;

      bf16x8 kf[4];
#pragma unroll
      for (int i = 0; i < 4; ++i)
        kf[i] = *reinterpret_cast<const bf16x8*>(&Vc[kidx[i]]);

      // per set: S^T = mfma(K,Q) with C-init = -FIXMAX; exp2; permlane -> pfrag
      bf16x8 pfrag[2];
#pragma unroll
      for (int set = 0; set < 2; ++set) {
        f32x4 st[2];
        __builtin_amdgcn_s_setprio(1);
#pragma unroll
        for (int nt = 0; nt < 2; ++nt) {
          f32x4 acc = f32x4{-FIXMAX, -FIXMAX, -FIXMAX, -FIXMAX};
          acc = __builtin_amdgcn_mfma_f32_16x16x32_bf16(kf[nt * 2 + 0], qf[set][0], acc, 0, 0, 0);
          acc = __builtin_amdgcn_mfma_f32_16x16x32_bf16(kf[nt * 2 + 1], qf[set][1], acc, 0, 0, 0);
          st[nt] = acc;
        }
        __builtin_amdgcn_s_setprio(0);
        float p0 = __builtin_amdgcn_exp2f(st[0][0]);
        float p1 = __builtin_amdgcn_exp2f(st[0][1]);
        float p2 = __builtin_amdgcn_exp2f(st[0][2]);
        float p3 = __builtin_amdgcn_exp2f(st[0][3]);
        float p4 = __builtin_amdgcn_exp2f(st[1][0]);
        float p5 = __builtin_amdgcn_exp2f(st[1][1]);
        float p6 = __builtin_amdgcn_exp2f(st[1][2]);
        float p7 = __builtin_amdgcn_exp2f(st[1][3]);
        ls[set] += ((p0 + p1) + (p2 + p3)) + ((p4 + p5) + (p6 + p7));
        // P^T network: after p32+p16 swaps, a0/a1 = pfrag words 0/2, b0/b1 = 1/3.
        uint32_t a0 = pkcvt(p0, p1), b0 = pkcvt(p2, p3);
        uint32_t a1 = pkcvt(p4, p5), b1 = pkcvt(p6, p7);
        asm("v_permlane32_swap_b32 %0, %1" : "+v"(a0), "+v"(a1));
        asm("v_permlane16_swap_b32 %0, %1" : "+v"(a0), "+v"(a1));
        asm("v_permlane32_swap_b32 %0, %1" : "+v"(b0), "+v"(b1));
        asm("v_permlane16_swap_b32 %0, %1" : "+v"(b0), "+v"(b1));
        uint4 pw;
        pw.x = a0; pw.y = b0; pw.z = a1; pw.w = b1;
        pfrag[set] = __builtin_bit_cast(bf16x8, pw);
      }

      // PV: tr-reads feed both q-sets (R12 placement)
      {
        short4v tr[4][2];
#pragma unroll
        for (int et = 0; et < 4; ++et) {
          asm volatile("ds_read_b64_tr_b16 %0, %1 offset:%2"
                       : "=v"(tr[et][0]) : "v"(trbase), "i"(et * 512));
          asm volatile("ds_read_b64_tr_b16 %0, %1 offset:%2"
                       : "=v"(tr[et][1]) : "v"(trbase), "i"((4 + et) * 512));
        }
        asm volatile("s_waitcnt lgkmcnt(0)" ::: "memory");
        __builtin_amdgcn_sched_barrier(0); // rule #18

        __builtin_amdgcn_s_setprio(1);
#pragma unroll
        for (int et = 0; et < 4; ++et) {
          short4v lo = tr[et][0], hi = tr[et][1];
          bf16x8 vf;
          vf[0] = lo[0]; vf[1] = lo[1]; vf[2] = lo[2]; vf[3] = lo[3];
          vf[4] = hi[0]; vf[5] = hi[1]; vf[6] = hi[2]; vf[7] = hi[3];
#pragma unroll
          for (int set = 0; set < 2; ++set)
            oacc[set][et] = __builtin_amdgcn_mfma_f32_16x16x32_bf16(vf, pfrag[set], oacc[set][et], 0, 0, 0);
        }
        __builtin_amdgcn_s_setprio(0);
      }
      cur ^= 1;
    }

    // reduce l across g (sum only; fixed max)
#pragma unroll
    for (int set = 0; set < 2; ++set) {
      ls[set] += __shfl_xor(ls[set], 16);
      ls[set] += __shfl_xor(ls[set], 32);
    }

    // write own partials: O slices land exactly in own Vq[wid]; l in own SB slots
#pragma unroll
    for (int set = 0; set < 2; ++set) {
#pragma unroll
      for (int et = 0; et < 4; ++et)
        *reinterpret_cast<f32x4*>(&mrg[(((wid * 2 + set) * 4 + et) * 64 + lane) * 4]) =
            oacc[set][et];
      ml[(wid * 2 + set) * 64 + lane] = ls[set];
    }
    __syncthreads();

    if (pass == 0) {
      // each wave merges et == wid; stash merged q (pre-scaled bf16) for broadcast
      uint2 qw[2];
#pragma unroll
      for (int set = 0; set < 2; ++set) {
        float lt = 0.f;
#pragma unroll
        for (int w = 0; w < 4; ++w) lt += ml[(w * 2 + set) * 64 + lane];
        float fac = SCALE2 / lt;
        f32x4 Ot = f32x4{0.f, 0.f, 0.f, 0.f};
#pragma unroll
        for (int w = 0; w < 4; ++w)
          Ot += *reinterpret_cast<const f32x4*>(&mrg[(((w * 2 + set) * 4 + wid) * 64 + lane) * 4]);
        qw[set].x = pkcvt(Ot[0] * fac, Ot[1] * fac);
        qw[set].y = pkcvt(Ot[2] * fac, Ot[3] * fac);
      }
      __syncthreads(); // all ml reads done before qls overwrites SB
#pragma unroll
      for (int set = 0; set < 2; ++set)
        *reinterpret_cast<uint2*>(&qls[(set * 16 + qi) * 64 + wid * 16 + 4 * g]) = qw[set];
      __syncthreads();
#pragma unroll
      for (int set = 0; set < 2; ++set)
#pragma unroll
        for (int eck = 0; eck < 2; ++eck)
          qf[set][eck] = *reinterpret_cast<const bf16x8*>(
              &qls[(set * 16 + qi) * 64 + eck * 32 + 8 * g]);
      __syncthreads(); // qf reads complete before pass-1 DMA/ml writes
    } else {
      if (wid == 0) {
#pragma unroll
        for (int set = 0; set < 2; ++set) {
          float lt = 0.f;
#pragma unroll
          for (int w = 0; w < 4; ++w) lt += ml[(w * 2 + set) * 64 + lane];
          float inv = 1.0f / lt;
#pragma unroll
          for (int et = 0; et < 4; ++et) {
            f32x4 Ot = f32x4{0.f, 0.f, 0.f, 0.f};
#pragma unroll
            for (int w = 0; w < 4; ++w)
              Ot += *reinterpret_cast<const f32x4*>(&mrg[(((w * 2 + set) * 4 + et) * 64 + lane) * 4]);
            float4 o;
            o.x = Ot[0] * inv; o.y = Ot[1] * inv; o.z = Ot[2] * inv; o.w = Ot[3] * inv;
            *reinterpret_cast<float4*>(&outF[qbase[set] + et * 16 + 4 * g]) = o;
          }
        }
      }
    }
  }
}

extern "C" void kernel_launch(void* const* d_in, const int* in_sizes, int n_in,
                              void* d_out, int out_size, void* d_ws, size_t ws_size,
                              hipStream_t stream) {
  const float* R = (const float*)d_in[0];
  const float* Y = (const float*)d_in[1];
  float* outF = (float*)d_out;

  constexpr int NE = B_ * S_ * DM_; // 2,097,152 elements
  ushort* Yb = (ushort*)d_ws;

  const int n4 = NE / 4;
  cvt_kernel<<<dim3((n4 + 255) / 256), 256, 0, stream>>>(Y, Yb, n4);

  const int ngrid = B_ * H_ * (L_ / 32); // 1024 workgroups = 4 wg/CU
  hopfield_kernel<<<dim3(ngrid), 256, 0, stream>>>(R, Yb, outF);
}

// Round 15
// 54.876 us; speedup vs baseline: 1.0458x; 1.0458x over previous
//
#include <hip/hip_runtime.h>
#include <hip/hip_bf16.h>
#include <cstdint>

// HopfieldLayer: out = attn(attn(R,Y,Y), Y, Y), H=8, E=64, scale 1/8.
// R15: R12 restored verbatim (lacc ones-MFMA back -- R14 proved it faster than
// VALU ls) + ONE change: tr-reads hoisted between the QK MFMA cluster and the
// softmax VALU block, so their LDS latency hides under exp2/pack/permlane.
// This is the second half of the R13 bisect (DMA offset:64 stays reverted).

typedef __attribute__((ext_vector_type(8))) short bf16x8;
typedef __attribute__((ext_vector_type(4))) short short4v;
typedef __attribute__((ext_vector_type(4))) float f32x4;

constexpr int B_ = 2, L_ = 2048, S_ = 2048, H_ = 8, E_ = 64, DM_ = 512;
constexpr int NTQ_ = 16; // 32-s tiles per S-quarter (512 s)
constexpr float SCALE2 = 0.18033688011112042f; // (1/sqrt(64)) * log2(e)
constexpr float FIXMAX = 24.0f;                // fixed softmax max (exp2 domain)

__device__ __forceinline__ ushort f2bf(float a) {
  uint32_t u = __builtin_bit_cast(uint32_t, a);
  return (ushort)((u + 0x7fffu + ((u >> 16) & 1u)) >> 16); // RNE, finite inputs
}
__device__ __forceinline__ uint32_t pkcvt(float lo, float hi) {
  uint32_t r; // D[15:0] = bf16(S0=lo), D[31:16] = bf16(S1=hi)
  asm("v_cvt_pk_bf16_f32 %0, %1, %2" : "=v"(r) : "v"(lo), "v"(hi));
  return r;
}
__device__ __forceinline__ void dma16(const ushort* g, const ushort* l) {
  __builtin_amdgcn_global_load_lds(
      (const __attribute__((address_space(1))) uint32_t*)g,
      (__attribute__((address_space(3))) uint32_t*)l, 16, 0, 0);
}

__global__ void cvt_kernel(const float* __restrict__ in, ushort* __restrict__ out, int n4) {
  int i = blockIdx.x * 256 + threadIdx.x;
  if (i >= n4) return;
  float4 v = reinterpret_cast<const float4*>(in)[i];
  ushort4 o;
  o.x = f2bf(v.x); o.y = f2bf(v.y); o.z = f2bf(v.z); o.w = f2bf(v.w);
  reinterpret_cast<ushort4*>(out)[i] = o;
}

// KV LDS tile: 32s x 64e bf16, sub-tiled for tr-reads (R8-R12-proven):
//   idx(s,e) = block*64 + (s&3)*16 + (e&15),
//   block = (((s>>2)&1)*4 + (e>>4))*4 + (s>>3)
// DMA chunk c (16 B) at byte c*16 holds s = (blk&3)*8 + ((blk>>4)&1)*4 +
//   ((c>>1)&3), e0 = ((blk>>2)&3)*16 + (c&1)*8, blk = c>>3.
__global__ __launch_bounds__(256, 4) void hopfield_kernel(
    const float* __restrict__ Rf, const ushort* __restrict__ Yb,
    float* __restrict__ outF) {
  __shared__ ushort Vq[4][2][2048]; // 32 KB; merge-partial overlay (own slices)
  __shared__ uint32_t SB[1024];     // 4 KB: ml, then q-broadcast (pass 0)

  const int tid = threadIdx.x, lane = tid & 63, wid = tid >> 6;
  const int g = lane >> 4, qi = lane & 15;
  // bijective XCD swizzle: XCD k (= orig%8) owns 128 contiguous logical wgs
  const int wg = (blockIdx.x & 7) * 128 + (blockIdx.x >> 3);
  const int qt = wg & 63, h = (wg >> 6) & 7, b = wg >> 9;

  size_t qbase[2];
#pragma unroll
  for (int set = 0; set < 2; ++set)
    qbase[set] = (size_t)(b * L_ + qt * 32 + set * 16 + qi) * DM_ + h * E_;

  // pass-0 Q frags: read R f32, scale, pack to bf16 (cvt_pk)
  bf16x8 qf[2][2];
#pragma unroll
  for (int set = 0; set < 2; ++set)
#pragma unroll
    for (int eck = 0; eck < 2; ++eck) {
      const float* s = Rf + qbase[set] + eck * 32 + 8 * g;
      float4 aa = *reinterpret_cast<const float4*>(s);
      float4 bb = *reinterpret_cast<const float4*>(s + 4);
      uint4 w;
      w.x = pkcvt(aa.x * SCALE2, aa.y * SCALE2);
      w.y = pkcvt(aa.z * SCALE2, aa.w * SCALE2);
      w.z = pkcvt(bb.x * SCALE2, bb.y * SCALE2);
      w.w = pkcvt(bb.z * SCALE2, bb.w * SCALE2);
      qf[set][eck] = __builtin_bit_cast(bf16x8, w);
    }

  const size_t ybase = (size_t)(b * S_ + wid * 512) * DM_ + h * E_;

  // per-lane DMA global sources (pre-swizzled to match the sub-tiled layout)
  const ushort* gdma[4];
#pragma unroll
  for (int i = 0; i < 4; ++i) {
    int c = i * 64 + lane, blk = c >> 3;
    int s = (blk & 3) * 8 + ((blk >> 4) & 1) * 4 + ((c >> 1) & 3);
    int e0 = ((blk >> 2) & 3) * 16 + (c & 1) * 8;
    gdma[i] = Yb + ybase + (size_t)s * DM_ + e0;
  }

  int kidx[4];
#pragma unroll
  for (int nt = 0; nt < 2; ++nt)
#pragma unroll
    for (int eck = 0; eck < 2; ++eck) {
      int s = nt * 16 + qi;
      kidx[nt * 2 + eck] = ((((s >> 2) & 1) * 4 + (eck * 2 + (g >> 1))) * 4 + (s >> 3)) * 64 +
                           (s & 3) * 16 + 8 * (g & 1);
    }

  // ones A-frag for the l-row-sum MFMA (bf16 1.0 = 0x3F80)
  uint4 ou;
  ou.x = ou.y = ou.z = ou.w = 0x3F803F80u;
  const bf16x8 ones = __builtin_bit_cast(bf16x8, ou);

  const uint32_t vb0 = (uint32_t)(uintptr_t)(&Vq[wid][0][0]);
  float* mrg = (float*)&Vq[0][0][0];
  float* ml = (float*)&SB[0];
  ushort* qls = (ushort*)&SB[0];

  for (int pass = 0; pass < 2; ++pass) {
    f32x4 oacc[2][4], lacc[2];
#pragma unroll
    for (int set = 0; set < 2; ++set) {
#pragma unroll
      for (int et = 0; et < 4; ++et) oacc[set][et] = f32x4{0.f, 0.f, 0.f, 0.f};
      lacc[set] = f32x4{0.f, 0.f, 0.f, 0.f};
    }

    // prologue: DMA tile 0 into buffer 0 (wave-private slice)
#pragma unroll
    for (int i = 0; i < 4; ++i) dma16(gdma[i], &Vq[wid][0][i * 512]);
    int cur = 0;

    for (int t = 0; t < NTQ_; ++t) {
      asm volatile("s_waitcnt vmcnt(0)" ::: "memory"); // tile t resident
      if (t + 1 < NTQ_) { // issue next tile a full iteration ahead
        const size_t tadd = (size_t)(t + 1) * 32 * DM_;
#pragma unroll
        for (int i = 0; i < 4; ++i)
          dma16(gdma[i] + tadd, &Vq[wid][cur ^ 1][i * 512]);
      }

      const ushort* Vc = &Vq[wid][cur][0];
      const uint32_t trbase = vb0 + (uint32_t)(cur * 4096) + 8u * (uint32_t)lane;

      bf16x8 kf[4];
#pragma unroll
      for (int i = 0; i < 4; ++i)
        kf[i] = *reinterpret_cast<const bf16x8*>(&Vc[kidx[i]]);

      // QK^T for both sets, C-init = -FIXMAX
      f32x4 st[2][2];
      __builtin_amdgcn_s_setprio(1);
#pragma unroll
      for (int set = 0; set < 2; ++set)
#pragma unroll
        for (int nt = 0; nt < 2; ++nt) {
          f32x4 acc = f32x4{-FIXMAX, -FIXMAX, -FIXMAX, -FIXMAX};
          acc = __builtin_amdgcn_mfma_f32_16x16x32_bf16(kf[nt * 2 + 0], qf[set][0], acc, 0, 0, 0);
          acc = __builtin_amdgcn_mfma_f32_16x16x32_bf16(kf[nt * 2 + 1], qf[set][1], acc, 0, 0, 0);
          st[set][nt] = acc;
        }
      __builtin_amdgcn_s_setprio(0);

      // HOIST: V^T tr-reads issued now; latency hides under the softmax block
      short4v tr[4][2];
#pragma unroll
      for (int et = 0; et < 4; ++et) {
        asm volatile("ds_read_b64_tr_b16 %0, %1 offset:%2"
                     : "=v"(tr[et][0]) : "v"(trbase), "i"(et * 512));
        asm volatile("ds_read_b64_tr_b16 %0, %1 offset:%2"
                     : "=v"(tr[et][1]) : "v"(trbase), "i"((4 + et) * 512));
      }

      // softmax (fixed max) + permlane P^T -> pfrag, pure VALU
      bf16x8 pfrag[2];
#pragma unroll
      for (int set = 0; set < 2; ++set) {
        float p0 = __builtin_amdgcn_exp2f(st[set][0][0]);
        float p1 = __builtin_amdgcn_exp2f(st[set][0][1]);
        float p2 = __builtin_amdgcn_exp2f(st[set][0][2]);
        float p3 = __builtin_amdgcn_exp2f(st[set][0][3]);
        float p4 = __builtin_amdgcn_exp2f(st[set][1][0]);
        float p5 = __builtin_amdgcn_exp2f(st[set][1][1]);
        float p6 = __builtin_amdgcn_exp2f(st[set][1][2]);
        float p7 = __builtin_amdgcn_exp2f(st[set][1][3]);
        // P^T network: after p32+p16 swaps, a0/a1 = pfrag words 0/2, b0/b1 = 1/3.
        uint32_t a0 = pkcvt(p0, p1), b0 = pkcvt(p2, p3);
        uint32_t a1 = pkcvt(p4, p5), b1 = pkcvt(p6, p7);
        asm("v_permlane32_swap_b32 %0, %1" : "+v"(a0), "+v"(a1));
        asm("v_permlane16_swap_b32 %0, %1" : "+v"(a0), "+v"(a1));
        asm("v_permlane32_swap_b32 %0, %1" : "+v"(b0), "+v"(b1));
        asm("v_permlane16_swap_b32 %0, %1" : "+v"(b0), "+v"(b1));
        uint4 pw;
        pw.x = a0; pw.y = b0; pw.z = a1; pw.w = b1;
        pfrag[set] = __builtin_bit_cast(bf16x8, pw);
      }

      // tr data ready; rule #18 fence, then PV (+ l-row-sum via ones-MFMA)
      asm volatile("s_waitcnt lgkmcnt(0)" ::: "memory");
      __builtin_amdgcn_sched_barrier(0);

      __builtin_amdgcn_s_setprio(1);
#pragma unroll
      for (int set = 0; set < 2; ++set)
        lacc[set] = __builtin_amdgcn_mfma_f32_16x16x32_bf16(ones, pfrag[set], lacc[set], 0, 0, 0);
#pragma unroll
      for (int et = 0; et < 4; ++et) {
        short4v lo = tr[et][0], hi = tr[et][1];
        bf16x8 vf;
        vf[0] = lo[0]; vf[1] = lo[1]; vf[2] = lo[2]; vf[3] = lo[3];
        vf[4] = hi[0]; vf[5] = hi[1]; vf[6] = hi[2]; vf[7] = hi[3];
#pragma unroll
        for (int set = 0; set < 2; ++set)
          oacc[set][et] = __builtin_amdgcn_mfma_f32_16x16x32_bf16(vf, pfrag[set], oacc[set][et], 0, 0, 0);
      }
      __builtin_amdgcn_s_setprio(0);
      cur ^= 1;
    }

    // l is in lacc[set][0] (all rows of the ones-MFMA output are equal)
#pragma unroll
    for (int set = 0; set < 2; ++set) {
#pragma unroll
      for (int et = 0; et < 4; ++et)
        *reinterpret_cast<f32x4*>(&mrg[(((wid * 2 + set) * 4 + et) * 64 + lane) * 4]) =
            oacc[set][et];
      ml[(wid * 2 + set) * 64 + lane] = lacc[set][0];
    }
    __syncthreads();

    if (pass == 0) {
      // each wave merges et == wid; stash merged q (pre-scaled bf16) for broadcast
      uint2 qw[2];
#pragma unroll
      for (int set = 0; set < 2; ++set) {
        float lt = 0.f;
#pragma unroll
        for (int w = 0; w < 4; ++w) lt += ml[(w * 2 + set) * 64 + lane];
        float fac = SCALE2 / lt;
        f32x4 Ot = f32x4{0.f, 0.f, 0.f, 0.f};
#pragma unroll
        for (int w = 0; w < 4; ++w)
          Ot += *reinterpret_cast<const f32x4*>(&mrg[(((w * 2 + set) * 4 + wid) * 64 + lane) * 4]);
        qw[set].x = pkcvt(Ot[0] * fac, Ot[1] * fac);
        qw[set].y = pkcvt(Ot[2] * fac, Ot[3] * fac);
      }
      __syncthreads(); // all ml reads done before qls overwrites SB
#pragma unroll
      for (int set = 0; set < 2; ++set)
        *reinterpret_cast<uint2*>(&qls[(set * 16 + qi) * 64 + wid * 16 + 4 * g]) = qw[set];
      __syncthreads();
#pragma unroll
      for (int set = 0; set < 2; ++set)
#pragma unroll
        for (int eck = 0; eck < 2; ++eck)
          qf[set][eck] = *reinterpret_cast<const bf16x8*>(
              &qls[(set * 16 + qi) * 64 + eck * 32 + 8 * g]);
      __syncthreads(); // qf reads complete before pass-1 DMA/ml writes
    } else {
      if (wid == 0) {
#pragma unroll
        for (int set = 0; set < 2; ++set) {
          float lt = 0.f;
#pragma unroll
          for (int w = 0; w < 4; ++w) lt += ml[(w * 2 + set) * 64 + lane];
          float inv = 1.0f / lt;
#pragma unroll
          for (int et = 0; et < 4; ++et) {
            f32x4 Ot = f32x4{0.f, 0.f, 0.f, 0.f};
#pragma unroll
            for (int w = 0; w < 4; ++w)
              Ot += *reinterpret_cast<const f32x4*>(&mrg[(((w * 2 + set) * 4 + et) * 64 + lane) * 4]);
            float4 o;
            o.x = Ot[0] * inv; o.y = Ot[1] * inv; o.z = Ot[2] * inv; o.w = Ot[3] * inv;
            *reinterpret_cast<float4*>(&outF[qbase[set] + et * 16 + 4 * g]) = o;
          }
        }
      }
    }
  }
}

extern "C" void kernel_launch(void* const* d_in, const int* in_sizes, int n_in,
                              void* d_out, int out_size, void* d_ws, size_t ws_size,
                              hipStream_t stream) {
  const float* R = (const float*)d_in[0];
  const float* Y = (const float*)d_in[1];
  float* outF = (float*)d_out;

  constexpr int NE = B_ * S_ * DM_; // 2,097,152 elements
  ushort* Yb = (ushort*)d_ws;

  const int n4 = NE / 4;
  cvt_kernel<<<dim3((n4 + 255) / 256), 256, 0, stream>>>(Y, Yb, n4);

  const int ngrid = B_ * H_ * (L_ / 32); // 1024 workgroups = 4 wg/CU
  hopfield_kernel<<<dim3(ngrid), 256, 0, stream>>>(R, Yb, outF);
}

// Round 16
// 53.059 us; speedup vs baseline: 1.0816x; 1.0342x over previous
//
#include <hip/hip_runtime.h>
#include <hip/hip_bf16.h>
#include <cstdint>

// HopfieldLayer: out = attn(attn(R,Y,Y), Y, Y), H=8, E=64, scale 1/8.
// R16: zero-register issue-order tuning on R15. (1) per-set interleave:
// QK_set0 -> tr-issue -> QK_set1 -> softmax0 -> softmax1 (pads both QK->softmax
// dependency chains); (2) kf ds_reads issued before the DMA quad; (3) cvt
// kernel uses v_cvt_pk_bf16_f32. Everything else R15-verbatim.

typedef __attribute__((ext_vector_type(8))) short bf16x8;
typedef __attribute__((ext_vector_type(4))) short short4v;
typedef __attribute__((ext_vector_type(4))) float f32x4;

constexpr int B_ = 2, L_ = 2048, S_ = 2048, H_ = 8, E_ = 64, DM_ = 512;
constexpr int NTQ_ = 16; // 32-s tiles per S-quarter (512 s)
constexpr float SCALE2 = 0.18033688011112042f; // (1/sqrt(64)) * log2(e)
constexpr float FIXMAX = 24.0f;                // fixed softmax max (exp2 domain)

__device__ __forceinline__ uint32_t pkcvt(float lo, float hi) {
  uint32_t r; // D[15:0] = bf16(S0=lo), D[31:16] = bf16(S1=hi)
  asm("v_cvt_pk_bf16_f32 %0, %1, %2" : "=v"(r) : "v"(lo), "v"(hi));
  return r;
}
__device__ __forceinline__ void dma16(const ushort* g, const ushort* l) {
  __builtin_amdgcn_global_load_lds(
      (const __attribute__((address_space(1))) uint32_t*)g,
      (__attribute__((address_space(3))) uint32_t*)l, 16, 0, 0);
}

__global__ void cvt_kernel(const float* __restrict__ in, ushort* __restrict__ out, int n4) {
  int i = blockIdx.x * 256 + threadIdx.x;
  if (i >= n4) return;
  float4 v = reinterpret_cast<const float4*>(in)[i];
  uint2 o;
  o.x = pkcvt(v.x, v.y);
  o.y = pkcvt(v.z, v.w);
  reinterpret_cast<uint2*>(out)[i] = o;
}

// KV LDS tile: 32s x 64e bf16, sub-tiled for tr-reads (R8-R15-proven):
//   idx(s,e) = block*64 + (s&3)*16 + (e&15),
//   block = (((s>>2)&1)*4 + (e>>4))*4 + (s>>3)
// DMA chunk c (16 B) at byte c*16 holds s = (blk&3)*8 + ((blk>>4)&1)*4 +
//   ((c>>1)&3), e0 = ((blk>>2)&3)*16 + (c&1)*8, blk = c>>3.
__global__ __launch_bounds__(256, 4) void hopfield_kernel(
    const float* __restrict__ Rf, const ushort* __restrict__ Yb,
    float* __restrict__ outF) {
  __shared__ ushort Vq[4][2][2048]; // 32 KB; merge-partial overlay (own slices)
  __shared__ uint32_t SB[1024];     // 4 KB: ml, then q-broadcast (pass 0)

  const int tid = threadIdx.x, lane = tid & 63, wid = tid >> 6;
  const int g = lane >> 4, qi = lane & 15;
  // bijective XCD swizzle: XCD k (= orig%8) owns 128 contiguous logical wgs
  const int wg = (blockIdx.x & 7) * 128 + (blockIdx.x >> 3);
  const int qt = wg & 63, h = (wg >> 6) & 7, b = wg >> 9;

  size_t qbase[2];
#pragma unroll
  for (int set = 0; set < 2; ++set)
    qbase[set] = (size_t)(b * L_ + qt * 32 + set * 16 + qi) * DM_ + h * E_;

  // pass-0 Q frags: read R f32, scale, pack to bf16 (cvt_pk)
  bf16x8 qf[2][2];
#pragma unroll
  for (int set = 0; set < 2; ++set)
#pragma unroll
    for (int eck = 0; eck < 2; ++eck) {
      const float* s = Rf + qbase[set] + eck * 32 + 8 * g;
      float4 aa = *reinterpret_cast<const float4*>(s);
      float4 bb = *reinterpret_cast<const float4*>(s + 4);
      uint4 w;
      w.x = pkcvt(aa.x * SCALE2, aa.y * SCALE2);
      w.y = pkcvt(aa.z * SCALE2, aa.w * SCALE2);
      w.z = pkcvt(bb.x * SCALE2, bb.y * SCALE2);
      w.w = pkcvt(bb.z * SCALE2, bb.w * SCALE2);
      qf[set][eck] = __builtin_bit_cast(bf16x8, w);
    }

  const size_t ybase = (size_t)(b * S_ + wid * 512) * DM_ + h * E_;

  // per-lane DMA global sources (pre-swizzled to match the sub-tiled layout)
  const ushort* gdma[4];
#pragma unroll
  for (int i = 0; i < 4; ++i) {
    int c = i * 64 + lane, blk = c >> 3;
    int s = (blk & 3) * 8 + ((blk >> 4) & 1) * 4 + ((c >> 1) & 3);
    int e0 = ((blk >> 2) & 3) * 16 + (c & 1) * 8;
    gdma[i] = Yb + ybase + (size_t)s * DM_ + e0;
  }

  int kidx[4];
#pragma unroll
  for (int nt = 0; nt < 2; ++nt)
#pragma unroll
    for (int eck = 0; eck < 2; ++eck) {
      int s = nt * 16 + qi;
      kidx[nt * 2 + eck] = ((((s >> 2) & 1) * 4 + (eck * 2 + (g >> 1))) * 4 + (s >> 3)) * 64 +
                           (s & 3) * 16 + 8 * (g & 1);
    }

  // ones A-frag for the l-row-sum MFMA (bf16 1.0 = 0x3F80)
  uint4 ou;
  ou.x = ou.y = ou.z = ou.w = 0x3F803F80u;
  const bf16x8 ones = __builtin_bit_cast(bf16x8, ou);

  const uint32_t vb0 = (uint32_t)(uintptr_t)(&Vq[wid][0][0]);
  float* mrg = (float*)&Vq[0][0][0];
  float* ml = (float*)&SB[0];
  ushort* qls = (ushort*)&SB[0];

  for (int pass = 0; pass < 2; ++pass) {
    f32x4 oacc[2][4], lacc[2];
#pragma unroll
    for (int set = 0; set < 2; ++set) {
#pragma unroll
      for (int et = 0; et < 4; ++et) oacc[set][et] = f32x4{0.f, 0.f, 0.f, 0.f};
      lacc[set] = f32x4{0.f, 0.f, 0.f, 0.f};
    }

    // prologue: DMA tile 0 into buffer 0 (wave-private slice)
#pragma unroll
    for (int i = 0; i < 4; ++i) dma16(gdma[i], &Vq[wid][0][i * 512]);
    int cur = 0;

    for (int t = 0; t < NTQ_; ++t) {
      asm volatile("s_waitcnt vmcnt(0)" ::: "memory"); // tile t resident

      const ushort* Vc = &Vq[wid][cur][0];
      const uint32_t trbase = vb0 + (uint32_t)(cur * 4096) + 8u * (uint32_t)lane;

      // K A-frags first (kf->QK chain starts immediately)
      bf16x8 kf[4];
#pragma unroll
      for (int i = 0; i < 4; ++i)
        kf[i] = *reinterpret_cast<const bf16x8*>(&Vc[kidx[i]]);

      // next tile's DMA after the kf issue (full-iteration latency cover)
      if (t + 1 < NTQ_) {
        const size_t tadd = (size_t)(t + 1) * 32 * DM_;
#pragma unroll
        for (int i = 0; i < 4; ++i)
          dma16(gdma[i] + tadd, &Vq[wid][cur ^ 1][i * 512]);
      }

      // QK set0 -> tr issue -> QK set1 (pads QK0's result latency)
      f32x4 st[2][2];
      short4v tr[4][2];
      __builtin_amdgcn_s_setprio(1);
#pragma unroll
      for (int nt = 0; nt < 2; ++nt) {
        f32x4 acc = f32x4{-FIXMAX, -FIXMAX, -FIXMAX, -FIXMAX};
        acc = __builtin_amdgcn_mfma_f32_16x16x32_bf16(kf[nt * 2 + 0], qf[0][0], acc, 0, 0, 0);
        acc = __builtin_amdgcn_mfma_f32_16x16x32_bf16(kf[nt * 2 + 1], qf[0][1], acc, 0, 0, 0);
        st[0][nt] = acc;
      }
#pragma unroll
      for (int et = 0; et < 4; ++et) {
        asm volatile("ds_read_b64_tr_b16 %0, %1 offset:%2"
                     : "=v"(tr[et][0]) : "v"(trbase), "i"(et * 512));
        asm volatile("ds_read_b64_tr_b16 %0, %1 offset:%2"
                     : "=v"(tr[et][1]) : "v"(trbase), "i"((4 + et) * 512));
      }
#pragma unroll
      for (int nt = 0; nt < 2; ++nt) {
        f32x4 acc = f32x4{-FIXMAX, -FIXMAX, -FIXMAX, -FIXMAX};
        acc = __builtin_amdgcn_mfma_f32_16x16x32_bf16(kf[nt * 2 + 0], qf[1][0], acc, 0, 0, 0);
        acc = __builtin_amdgcn_mfma_f32_16x16x32_bf16(kf[nt * 2 + 1], qf[1][1], acc, 0, 0, 0);
        st[1][nt] = acc;
      }
      __builtin_amdgcn_s_setprio(0);

      // softmax set0 then set1 (set0's exp2 stalls covered by QK_set1 issue)
      bf16x8 pfrag[2];
#pragma unroll
      for (int set = 0; set < 2; ++set) {
        float p0 = __builtin_amdgcn_exp2f(st[set][0][0]);
        float p1 = __builtin_amdgcn_exp2f(st[set][0][1]);
        float p2 = __builtin_amdgcn_exp2f(st[set][0][2]);
        float p3 = __builtin_amdgcn_exp2f(st[set][0][3]);
        float p4 = __builtin_amdgcn_exp2f(st[set][1][0]);
        float p5 = __builtin_amdgcn_exp2f(st[set][1][1]);
        float p6 = __builtin_amdgcn_exp2f(st[set][1][2]);
        float p7 = __builtin_amdgcn_exp2f(st[set][1][3]);
        // P^T network: after p32+p16 swaps, a0/a1 = pfrag words 0/2, b0/b1 = 1/3.
        uint32_t a0 = pkcvt(p0, p1), b0 = pkcvt(p2, p3);
        uint32_t a1 = pkcvt(p4, p5), b1 = pkcvt(p6, p7);
        asm("v_permlane32_swap_b32 %0, %1" : "+v"(a0), "+v"(a1));
        asm("v_permlane16_swap_b32 %0, %1" : "+v"(a0), "+v"(a1));
        asm("v_permlane32_swap_b32 %0, %1" : "+v"(b0), "+v"(b1));
        asm("v_permlane16_swap_b32 %0, %1" : "+v"(b0), "+v"(b1));
        uint4 pw;
        pw.x = a0; pw.y = b0; pw.z = a1; pw.w = b1;
        pfrag[set] = __builtin_bit_cast(bf16x8, pw);
      }

      // tr data ready; rule #18 fence, then PV (+ l-row-sum via ones-MFMA)
      asm volatile("s_waitcnt lgkmcnt(0)" ::: "memory");
      __builtin_amdgcn_sched_barrier(0);

      __builtin_amdgcn_s_setprio(1);
#pragma unroll
      for (int set = 0; set < 2; ++set)
        lacc[set] = __builtin_amdgcn_mfma_f32_16x16x32_bf16(ones, pfrag[set], lacc[set], 0, 0, 0);
#pragma unroll
      for (int et = 0; et < 4; ++et) {
        short4v lo = tr[et][0], hi = tr[et][1];
        bf16x8 vf;
        vf[0] = lo[0]; vf[1] = lo[1]; vf[2] = lo[2]; vf[3] = lo[3];
        vf[4] = hi[0]; vf[5] = hi[1]; vf[6] = hi[2]; vf[7] = hi[3];
#pragma unroll
        for (int set = 0; set < 2; ++set)
          oacc[set][et] = __builtin_amdgcn_mfma_f32_16x16x32_bf16(vf, pfrag[set], oacc[set][et], 0, 0, 0);
      }
      __builtin_amdgcn_s_setprio(0);
      cur ^= 1;
    }

    // l is in lacc[set][0] (all rows of the ones-MFMA output are equal)
#pragma unroll
    for (int set = 0; set < 2; ++set) {
#pragma unroll
      for (int et = 0; et < 4; ++et)
        *reinterpret_cast<f32x4*>(&mrg[(((wid * 2 + set) * 4 + et) * 64 + lane) * 4]) =
            oacc[set][et];
      ml[(wid * 2 + set) * 64 + lane] = lacc[set][0];
    }
    __syncthreads();

    if (pass == 0) {
      // each wave merges et == wid; stash merged q (pre-scaled bf16) for broadcast
      uint2 qw[2];
#pragma unroll
      for (int set = 0; set < 2; ++set) {
        float lt = 0.f;
#pragma unroll
        for (int w = 0; w < 4; ++w) lt += ml[(w * 2 + set) * 64 + lane];
        float fac = SCALE2 / lt;
        f32x4 Ot = f32x4{0.f, 0.f, 0.f, 0.f};
#pragma unroll
        for (int w = 0; w < 4; ++w)
          Ot += *reinterpret_cast<const f32x4*>(&mrg[(((w * 2 + set) * 4 + wid) * 64 + lane) * 4]);
        qw[set].x = pkcvt(Ot[0] * fac, Ot[1] * fac);
        qw[set].y = pkcvt(Ot[2] * fac, Ot[3] * fac);
      }
      __syncthreads(); // all ml reads done before qls overwrites SB
#pragma unroll
      for (int set = 0; set < 2; ++set)
        *reinterpret_cast<uint2*>(&qls[(set * 16 + qi) * 64 + wid * 16 + 4 * g]) = qw[set];
      __syncthreads();
#pragma unroll
      for (int set = 0; set < 2; ++set)
#pragma unroll
        for (int eck = 0; eck < 2; ++eck)
          qf[set][eck] = *reinterpret_cast<const bf16x8*>(
              &qls[(set * 16 + qi) * 64 + eck * 32 + 8 * g]);
      __syncthreads(); // qf reads complete before pass-1 DMA/ml writes
    } else {
      if (wid == 0) {
#pragma unroll
        for (int set = 0; set < 2; ++set) {
          float lt = 0.f;
#pragma unroll
          for (int w = 0; w < 4; ++w) lt += ml[(w * 2 + set) * 64 + lane];
          float inv = 1.0f / lt;
#pragma unroll
          for (int et = 0; et < 4; ++et) {
            f32x4 Ot = f32x4{0.f, 0.f, 0.f, 0.f};
#pragma unroll
            for (int w = 0; w < 4; ++w)
              Ot += *reinterpret_cast<const f32x4*>(&mrg[(((w * 2 + set) * 4 + et) * 64 + lane) * 4]);
            float4 o;
            o.x = Ot[0] * inv; o.y = Ot[1] * inv; o.z = Ot[2] * inv; o.w = Ot[3] * inv;
            *reinterpret_cast<float4*>(&outF[qbase[set] + et * 16 + 4 * g]) = o;
          }
        }
      }
    }
  }
}

extern "C" void kernel_launch(void* const* d_in, const int* in_sizes, int n_in,
                              void* d_out, int out_size, void* d_ws, size_t ws_size,
                              hipStream_t stream) {
  const float* R = (const float*)d_in[0];
  const float* Y = (const float*)d_in[1];
  float* outF = (float*)d_out;

  constexpr int NE = B_ * S_ * DM_; // 2,097,152 elements
  ushort* Yb = (ushort*)d_ws;

  const int n4 = NE / 4;
  cvt_kernel<<<dim3((n4 + 255) / 256), 256, 0, stream>>>(Y, Yb, n4);

  const int ngrid = B_ * H_ * (L_ / 32); // 1024 workgroups = 4 wg/CU
  hopfield_kernel<<<dim3(ngrid), 256, 0, stream>>>(R, Yb, outF);
}